// Round 12
// baseline (10440.243 us; speedup 1.0000x reference)
//
#include <hip/hip_runtime.h>

typedef __attribute__((ext_vector_type(8))) short bf16x8;
typedef __attribute__((ext_vector_type(4))) float f32x4;

#define Tn 1024
#define Bn 64
#define Hn 2048
#define NBLK 128
#define NTHR 512

// ctrl word indices (each on its own 128B line)
#define ROOT_CTR     (16 * 32)

// watchdog: bounded spin so a liveness bug degrades to a wrong answer
// (diagnosable absmax failure) instead of a container-killing hang
#define SPIN_LIMIT (1u << 25)

__device__ __forceinline__ unsigned short f2b(float x) {
    // fp32 -> bf16 round-to-nearest-even
    unsigned u = __float_as_uint(x);
    return (unsigned short)((u + 0x7fffu + ((u >> 16) & 1u)) >> 16);
}
__device__ __forceinline__ float sigm(float x) {
    return __builtin_amdgcn_rcpf(1.0f + __expf(-x));
}
__device__ __forceinline__ float tanh_f(float x) {
    float e = __expf(2.0f * x);
    return 1.0f - 2.0f * __builtin_amdgcn_rcpf(1.0f + e);
}

// write-through system-scope stores: at MALL once vmcnt retires
__device__ __forceinline__ void store_short_wt(unsigned short* p, unsigned v) {
    asm volatile("global_store_short %0, %1, off sc0 sc1" :: "v"(p), "v"(v) : "memory");
}
__device__ __forceinline__ void store_dword_wt(float* p, float v) {
    asm volatile("global_store_dword %0, %1, off sc0 sc1" :: "v"(p), "v"(__float_as_uint(v)) : "memory");
}
__device__ __forceinline__ void store_u64_wt(unsigned long long* p, unsigned long long v) {
    asm volatile("global_store_dwordx2 %0, %1, off sc0 sc1" :: "v"(p), "v"(v) : "memory");
}
// Poll via atomic RMW(+0): the ONLY read primitive proven promptly coherent
// cross-XCD for atomically-updated lines (R1-R6 ablation). asm because
// InstCombine turns fetch_add(p,0) back into a plain atomic load.
__device__ __forceinline__ unsigned poll_read(unsigned* p) {
    unsigned old;
    asm volatile("global_atomic_add %0, %1, %2, off sc0 sc1\n\ts_waitcnt vmcnt(0)"
                 : "=v"(old) : "v"(p), "v"(0u) : "memory");
    return old;
}
// fresh h read: relaxed system-scope atomic load = global_load_dwordx2 sc0 sc1
// (bypasses L1/L2 -> reads MALL where WT stores land; compiler-tracked vmcnt).
__device__ __forceinline__ unsigned long long load_u64_bypass(const unsigned short* p) {
    return __hip_atomic_load((const unsigned long long*)p,
                             __ATOMIC_RELAXED, __HIP_MEMORY_SCOPE_SYSTEM);
}

// h fragment layout: h_f[kk][mt][laneF][e], kk=k>>5, mt=b>>4,
// laneF=((k>>3)&3)*16+(b&15), e=k&7. One MFMA A-frag = 64 lanes x 16B contig.
__device__ __forceinline__ long hfrag_off(int b, int k) {
    return ((long)(((k >> 5) * 4 + (b >> 4)) * 64) + ((k >> 3) & 3) * 16 + (b & 15)) * 8 + (k & 7);
}

// Prep: init_hidden fp32 -> bf16 h0 (frag layout, WT stores so the MALL copy
// is authoritative for gru's bypass loads); zero barrier ctrl (WT too).
__global__ void prep_kernel(const float* __restrict__ init_h,
                            unsigned short* __restrict__ h0,
                            unsigned* __restrict__ ctrl) {
    const int i = blockIdx.x * 256 + threadIdx.x;  // 0..32767
    const int b  = i >> 9;
    const int k4 = (i & 511) << 2;
    float4 v = *reinterpret_cast<const float4*>(init_h + (long)b * Hn + k4);
    unsigned long long q = (unsigned long long)f2b(v.x)
                         | ((unsigned long long)f2b(v.y) << 16)
                         | ((unsigned long long)f2b(v.z) << 32)
                         | ((unsigned long long)f2b(v.w) << 48);
    store_u64_wt((unsigned long long*)(h0 + hfrag_off(b, k4)), q);
    if (i < 2048)
        asm volatile("global_store_dword %0, %1, off sc0 sc1"
                     :: "v"(ctrl + i), "v"(0u) : "memory");
}

// Persistent GRU. 128 blocks x 512 threads (8 waves).
// Block bk owns 16 hidden units j in [16*bk, 16*bk+16).
// Wave w owns K-slice [256w, 256w+256); W rows live in REGISTERS (Bf[3][8]).
// K-loop: SOFTWARE-PIPELINED 16-load bursts (double-buffered hb[2][16]):
// burst kb+1's 16 independent 8B bypass loads issue BEFORE burst kb's 24
// MFMAs consume -> 3 of 4 MALL RTTs hidden. (R11: serialized bursts left
// ~2.5us of exposed latency. R10 lesson: keep VGPRs well under 256 —
// this needs ~160.)
// TWO-ROUND LDS reduction (48 KB; >64 KB static LDS kills launch, R7/R8).
// fp32 hidden state in registers at MFMA C-layout positions.
// NO fences / NO cache maintenance anywhere in the hot loop (R5 lesson).
// Barrier: FLAT — all 128 blocks RMW one counter, all poll it via RMW(+0)
// with s_sleep(2) backoff (removes the tree's closer-detect + leaf-flag
// hops ~1-1.5us; arrivals pipeline at the MALL).
__global__ void __launch_bounds__(NTHR, 2) gru_kernel(
    const float* __restrict__ inp,     // [T][B][3]
    const float* __restrict__ init_h,  // [B][H]
    const float* __restrict__ w_ih,    // [3H][3]
    const float* __restrict__ w_hh,    // [3H][H] fp32
    const float* __restrict__ bias,    // [3H]
    const float* __restrict__ bias_n,  // [H]
    unsigned short* __restrict__ h0,   // [B][H] bf16 frag-layout double buffer
    unsigned short* __restrict__ h1,
    unsigned* __restrict__ ctrl,       // [2048] barrier counters
    float* __restrict__ out)           // [T][B]
{
    __shared__ f32x4 red[4][4][3][64];  // [src][mt][nt][lane] = 48 KB

    const int tid  = threadIdx.x;
    const int lane = tid & 63;
    const int w    = tid >> 6;      // wave id = K-slice owner
    const int quad = lane >> 4;
    const int n16  = lane & 15;
    const int j0   = blockIdx.x * 16;
    const int jg   = j0 + n16;      // this lane's hidden column (epilogue)
    const int ks   = w * 256;

    // ---- preload W rows into registers as bf16 B-fragments (one-time) ----
    bf16x8 Bf[3][8];
    #pragma unroll
    for (int nt = 0; nt < 3; ++nt) {
        const long row = (long)(nt * Hn + j0 + n16);
        #pragma unroll
        for (int k = 0; k < 8; ++k) {
            const float* p = w_hh + row * Hn + ks + k * 32 + quad * 8;
            bf16x8 b;
            #pragma unroll
            for (int j = 0; j < 8; ++j) b[j] = (short)f2b(p[j]);
            Bf[nt][k] = b;
        }
    }

    // Epilogue constants (used by waves 0-3; all 64 lanes active)
    float wr0 = w_ih[jg*3+0], wr1 = w_ih[jg*3+1], wr2 = w_ih[jg*3+2];
    float wz0 = w_ih[(Hn+jg)*3+0], wz1 = w_ih[(Hn+jg)*3+1], wz2 = w_ih[(Hn+jg)*3+2];
    float wn0 = w_ih[(2*Hn+jg)*3+0], wn1 = w_ih[(2*Hn+jg)*3+1], wn2 = w_ih[(2*Hn+jg)*3+2];
    float br_ = bias[jg], bz_ = bias[Hn+jg], bn2_ = bias[2*Hn+jg];
    float bnn_ = bias_n[jg];

    // fp32 hidden state (waves 0-3; batch b = 16*w + quad*4 + r, col jg)
    float hst[4];
    if (w < 4) {
        #pragma unroll
        for (int r = 0; r < 4; ++r)
            hst[r] = init_h[(long)(16 * w + quad * 4 + r) * Hn + jg];
    }

    // epilogue frag-store decomposition of j = 16*bid + n16
    const int kkE = blockIdx.x >> 1;            // j>>5 (lane-uniform)
    const int qE  = (blockIdx.x & 1) * 2 + (n16 >> 3);
    const int eE  = n16 & 7;

    for (int t = 0; t < Tn; ++t) {
        const unsigned short* hcur = (t & 1) ? h1 : h0;
        unsigned short* hnext      = (t & 1) ? h0 : h1;

        // input contributions for this step (cached loads; inp is read-only)
        float xv[4][3];
        if (w < 4) {
            #pragma unroll
            for (int r = 0; r < 4; ++r) {
                const float* xp = inp + ((long)t * Bn + 16 * w + quad * 4 + r) * 3;
                xv[r][0] = xp[0]; xv[r][1] = xp[1]; xv[r][2] = xp[2];
            }
        }

        f32x4 acc[4][3];
        #pragma unroll
        for (int mt = 0; mt < 4; ++mt)
            #pragma unroll
            for (int nt = 0; nt < 3; ++nt)
                acc[mt][nt] = f32x4{0.f, 0.f, 0.f, 0.f};

        // wave's A-frag base: frag f=(k*4+mt) at short-offset f*512 + lane*8
        const unsigned short* pa = hcur + (long)(w * 8 * 4 * 64 + lane) * 8;

        // ---- software-pipelined bursts: issue kb+1 before consuming kb ----
        unsigned long long hb[2][16];
        #pragma unroll
        for (int f = 0; f < 8; ++f) {          // prologue: burst 0
            hb[0][2*f]   = load_u64_bypass(pa + (long)f * 512);
            hb[0][2*f+1] = load_u64_bypass(pa + (long)f * 512 + 4);
        }
        #pragma unroll
        for (int kb = 0; kb < 4; ++kb) {
            const int cur = kb & 1;
            if (kb < 3) {                      // prefetch burst kb+1
                const unsigned short* ph = pa + (long)((kb + 1) * 8) * 512;
                #pragma unroll
                for (int f = 0; f < 8; ++f) {
                    hb[cur ^ 1][2*f]   = load_u64_bypass(ph + (long)f * 512);
                    hb[cur ^ 1][2*f+1] = load_u64_bypass(ph + (long)f * 512 + 4);
                }
            }
            #pragma unroll
            for (int k2 = 0; k2 < 2; ++k2) {
                const int k = kb * 2 + k2;
                #pragma unroll
                for (int mt = 0; mt < 4; ++mt) {
                    const int f = k2 * 4 + mt;
                    union { unsigned long long q[2]; bf16x8 v; } u;
                    u.q[0] = hb[cur][2*f]; u.q[1] = hb[cur][2*f+1];
                    bf16x8 a = u.v;
                    acc[mt][0] = __builtin_amdgcn_mfma_f32_16x16x32_bf16(a, Bf[0][k], acc[mt][0], 0, 0, 0);
                    acc[mt][1] = __builtin_amdgcn_mfma_f32_16x16x32_bf16(a, Bf[1][k], acc[mt][1], 0, 0, 0);
                    acc[mt][2] = __builtin_amdgcn_mfma_f32_16x16x32_bf16(a, Bf[2][k], acc[mt][2], 0, 0, 0);
                }
            }
        }

        // ---- two-round cross-wave K reduction through LDS (48 KB) ----
        if (w >= 4) {
            #pragma unroll
            for (int mt = 0; mt < 4; ++mt)
                #pragma unroll
                for (int nt = 0; nt < 3; ++nt)
                    red[w - 4][mt][nt][lane] = acc[mt][nt];
        }
        __syncthreads();
        if (w < 4) {
            #pragma unroll
            for (int mt = 0; mt < 4; ++mt)
                #pragma unroll
                for (int nt = 0; nt < 3; ++nt)
                    acc[mt][nt] += red[w][mt][nt][lane];
        }
        __syncthreads();
        if (w < 4) {
            #pragma unroll
            for (int mt = 0; mt < 4; ++mt)
                #pragma unroll
                for (int nt = 0; nt < 3; ++nt)
                    red[w][mt][nt][lane] = acc[mt][nt];
        }
        __syncthreads();

        if (w < 4) {
            f32x4 s0 = red[0][w][0][lane], s1 = red[0][w][1][lane], s2 = red[0][w][2][lane];
            #pragma unroll
            for (int src = 1; src < 4; ++src) {
                s0 += red[src][w][0][lane];
                s1 += red[src][w][1][lane];
                s2 += red[src][w][2][lane];
            }
            #pragma unroll
            for (int r = 0; r < 4; ++r) {
                const int b = 16 * w + quad * 4 + r;
                float pr = br_ + wr0*xv[r][0] + wr1*xv[r][1] + wr2*xv[r][2] + s0[r];
                float pz = bz_ + wz0*xv[r][0] + wz1*xv[r][1] + wz2*xv[r][2] + s1[r];
                float rr = sigm(pr);
                float zz = sigm(pz);
                float pn = bn2_ + wn0*xv[r][0] + wn1*xv[r][1] + wn2*xv[r][2] + rr * (s2[r] + bnn_);
                float nn = tanh_f(pn);
                float hv = nn + zz * (hst[r] - nn);
                hst[r] = hv;
                store_short_wt(hnext + ((long)((kkE * 4 + w) * 64) + qE * 16 + quad * 4 + r) * 8 + eE,
                               (unsigned)f2b(hv));
                if (blockIdx.x == 0 && n16 == 0)
                    store_dword_wt(out + t * Bn + b, hv);
            }
        }

        // ---- FLAT grid barrier: one counter, RMW arrive, RMW(+0) poll ----
        __syncthreads();   // drains vmcnt(0) per wave -> WT stores at MALL
        if (tid == 0) {
            const unsigned tgt = (unsigned)NBLK * (unsigned)(t + 1);
            __hip_atomic_fetch_add(&ctrl[ROOT_CTR], 1u,
                                   __ATOMIC_RELAXED, __HIP_MEMORY_SCOPE_SYSTEM);
            unsigned spins = 0;
            while (poll_read(&ctrl[ROOT_CTR]) < tgt) {
                __builtin_amdgcn_s_sleep(2);
                if (++spins > SPIN_LIMIT) break;   // watchdog
            }
        }
        __syncthreads();
    }
}

extern "C" void kernel_launch(void* const* d_in, const int* in_sizes, int n_in,
                              void* d_out, int out_size, void* d_ws, size_t ws_size,
                              hipStream_t stream) {
    const float* inp    = (const float*)d_in[0];  // [1024][64][3]
    const float* init_h = (const float*)d_in[1];  // [64][2048]
    const float* w_ih   = (const float*)d_in[2];  // [6144][3]
    const float* w_hh   = (const float*)d_in[3];  // [6144][2048]
    const float* bias   = (const float*)d_in[4];  // [6144]
    const float* bias_n = (const float*)d_in[5];  // [2048]
    float* out = (float*)d_out;                   // [1024][64]

    unsigned short* h0 = (unsigned short*)d_ws;          // 262144 B
    unsigned short* h1 = h0 + 131072L;                   // 262144 B
    unsigned* ctrl     = (unsigned*)(h1 + 131072L);      // 8192 B

    prep_kernel<<<128, 256, 0, stream>>>(init_h, h0, ctrl);
    gru_kernel<<<NBLK, NTHR, 0, stream>>>(inp, init_h, w_ih, w_hh, bias, bias_n,
                                          h0, h1, ctrl, out);
}

// Round 13
// 6257.400 us; speedup vs baseline: 1.6685x; 1.6685x over previous
//
#include <hip/hip_runtime.h>

typedef __attribute__((ext_vector_type(8))) short bf16x8;
typedef __attribute__((ext_vector_type(4))) float f32x4;
typedef __attribute__((ext_vector_type(4))) int i32x4;

#define Tn 1024
#define Bn 64
#define Hn 2048
#define NBLK 128
#define NTHR 512

// ctrl word indices (each on its own 128B line)
#define LEAF_CTR(i)  ((i) * 32)
#define ROOT_CTR     (16 * 32)
#define LEAF_FLAG(i) ((18 + (i)) * 32)

// watchdog: bounded spin so a liveness bug degrades to a wrong answer
// (diagnosable absmax failure) instead of a container-killing hang
#define SPIN_LIMIT (1u << 25)

__device__ __forceinline__ unsigned short f2b(float x) {
    // fp32 -> bf16 round-to-nearest-even
    unsigned u = __float_as_uint(x);
    return (unsigned short)((u + 0x7fffu + ((u >> 16) & 1u)) >> 16);
}
__device__ __forceinline__ float sigm(float x) {
    return __builtin_amdgcn_rcpf(1.0f + __expf(-x));
}
__device__ __forceinline__ float tanh_f(float x) {
    float e = __expf(2.0f * x);
    return 1.0f - 2.0f * __builtin_amdgcn_rcpf(1.0f + e);
}

// write-through system-scope stores: at MALL once vmcnt retires
__device__ __forceinline__ void store_short_wt(unsigned short* p, unsigned v) {
    asm volatile("global_store_short %0, %1, off sc0 sc1" :: "v"(p), "v"(v) : "memory");
}
__device__ __forceinline__ void store_dword_wt(float* p, float v) {
    asm volatile("global_store_dword %0, %1, off sc0 sc1" :: "v"(p), "v"(__float_as_uint(v)) : "memory");
}
__device__ __forceinline__ void store_u64_wt(unsigned long long* p, unsigned long long v) {
    asm volatile("global_store_dwordx2 %0, %1, off sc0 sc1" :: "v"(p), "v"(v) : "memory");
}
// Poll via atomic RMW(+0): the ONLY read primitive proven promptly coherent
// cross-XCD for ATOMICALLY-updated lines (R1-R6 ablation). asm because
// InstCombine turns fetch_add(p,0) back into a plain atomic load.
__device__ __forceinline__ unsigned poll_read(unsigned* p) {
    unsigned old;
    asm volatile("global_atomic_add %0, %1, %2, off sc0 sc1\n\ts_waitcnt vmcnt(0)"
                 : "=v"(old) : "v"(p), "v"(0u) : "memory");
    return old;
}

// h fragment layout: h_f[kk][mt][laneF][e], kk=k>>5, mt=b>>4,
// laneF=((k>>3)&3)*16+(b&15), e=k&7. One MFMA A-frag = 64 lanes x 16B contig.
__device__ __forceinline__ long hfrag_off(int b, int k) {
    return ((long)(((k >> 5) * 4 + (b >> 4)) * 64) + ((k >> 3) & 3) * 16 + (b & 15)) * 8 + (k & 7);
}

// Prep: init_hidden fp32 -> bf16 h0 (frag layout, WT stores so the MALL copy
// is authoritative for gru's bypass loads); zero barrier ctrl (WT too).
__global__ void prep_kernel(const float* __restrict__ init_h,
                            unsigned short* __restrict__ h0,
                            unsigned* __restrict__ ctrl) {
    const int i = blockIdx.x * 256 + threadIdx.x;  // 0..32767
    const int b  = i >> 9;
    const int k4 = (i & 511) << 2;
    float4 v = *reinterpret_cast<const float4*>(init_h + (long)b * Hn + k4);
    unsigned long long q = (unsigned long long)f2b(v.x)
                         | ((unsigned long long)f2b(v.y) << 16)
                         | ((unsigned long long)f2b(v.z) << 32)
                         | ((unsigned long long)f2b(v.w) << 48);
    store_u64_wt((unsigned long long*)(h0 + hfrag_off(b, k4)), q);
    if (i < 2048)
        asm volatile("global_store_dword %0, %1, off sc0 sc1"
                     :: "v"(ctrl + i), "v"(0u) : "memory");
}

// Persistent GRU. 128 blocks x 512 threads (8 waves).
// Block bk owns 16 hidden units j in [16*bk, 16*bk+16).
// Wave w owns K-slice [256w, 256w+256); W rows live in REGISTERS (Bf[3][8]).
// K-loop: 2 ASM-PINNED bursts of 16x global_load_dwordx4 sc0/sc1 (one load
// per A-frag, 16B/lane coalescing sweet spot), each followed by a single
// s_waitcnt vmcnt(0) that carries the 16 buffers as "+v" operands (dataflow
// ties the MFMAs to the waitcnt -> no hoist hazard; compiler cannot sink the
// loads as it did to R12's C-level pipeline). Exposed MALL RTTs: 4 (R11) -> 2.
// Bypass plain-loads of WT-stored data are proven coherent (R6+: the
// "atomic relaxed" h loads compile to exactly this encoding).
// TWO-ROUND LDS reduction (48 KB; >64 KB static LDS kills launch, R7/R8).
// fp32 hidden state in registers at MFMA C-layout positions.
// NO fences / NO cache maintenance anywhere in the hot loop (R5 lesson).
// Barrier (R11-proven tree): leaf arrive RMW -> closer root RMW -> closers
// poll root counter -> leaf flag RMW -> members poll. All polls RMW(+0).
// (R12's flat single-counter barrier regressed ~1.5us/step: 128 pollers'
// RMWs serialized against arrivals on one line.)
__global__ void __launch_bounds__(NTHR, 2) gru_kernel(
    const float* __restrict__ inp,     // [T][B][3]
    const float* __restrict__ init_h,  // [B][H]
    const float* __restrict__ w_ih,    // [3H][3]
    const float* __restrict__ w_hh,    // [3H][H] fp32
    const float* __restrict__ bias,    // [3H]
    const float* __restrict__ bias_n,  // [H]
    unsigned short* __restrict__ h0,   // [B][H] bf16 frag-layout double buffer
    unsigned short* __restrict__ h1,
    unsigned* __restrict__ ctrl,       // [2048] barrier counters + flags
    float* __restrict__ out)           // [T][B]
{
    __shared__ f32x4 red[4][4][3][64];  // [src][mt][nt][lane] = 48 KB

    const int tid  = threadIdx.x;
    const int lane = tid & 63;
    const int w    = tid >> 6;      // wave id = K-slice owner
    const int quad = lane >> 4;
    const int n16  = lane & 15;
    const int j0   = blockIdx.x * 16;
    const int jg   = j0 + n16;      // this lane's hidden column (epilogue)
    const int ks   = w * 256;

    // ---- preload W rows into registers as bf16 B-fragments (one-time) ----
    bf16x8 Bf[3][8];
    #pragma unroll
    for (int nt = 0; nt < 3; ++nt) {
        const long row = (long)(nt * Hn + j0 + n16);
        #pragma unroll
        for (int k = 0; k < 8; ++k) {
            const float* p = w_hh + row * Hn + ks + k * 32 + quad * 8;
            bf16x8 b;
            #pragma unroll
            for (int j = 0; j < 8; ++j) b[j] = (short)f2b(p[j]);
            Bf[nt][k] = b;
        }
    }

    // Epilogue constants (used by waves 0-3; all 64 lanes active)
    float wr0 = w_ih[jg*3+0], wr1 = w_ih[jg*3+1], wr2 = w_ih[jg*3+2];
    float wz0 = w_ih[(Hn+jg)*3+0], wz1 = w_ih[(Hn+jg)*3+1], wz2 = w_ih[(Hn+jg)*3+2];
    float wn0 = w_ih[(2*Hn+jg)*3+0], wn1 = w_ih[(2*Hn+jg)*3+1], wn2 = w_ih[(2*Hn+jg)*3+2];
    float br_ = bias[jg], bz_ = bias[Hn+jg], bn2_ = bias[2*Hn+jg];
    float bnn_ = bias_n[jg];

    // fp32 hidden state (waves 0-3; batch b = 16*w + quad*4 + r, col jg)
    float hst[4];
    if (w < 4) {
        #pragma unroll
        for (int r = 0; r < 4; ++r)
            hst[r] = init_h[(long)(16 * w + quad * 4 + r) * Hn + jg];
    }

    // epilogue frag-store decomposition of j = 16*bid + n16
    const int kkE = blockIdx.x >> 1;            // j>>5 (lane-uniform)
    const int qE  = (blockIdx.x & 1) * 2 + (n16 >> 3);
    const int eE  = n16 & 7;

    const int leaf = blockIdx.x >> 3;           // 16 leaves x 8 blocks

    for (int t = 0; t < Tn; ++t) {
        const unsigned short* hcur = (t & 1) ? h1 : h0;
        unsigned short* hnext      = (t & 1) ? h0 : h1;

        // input contributions for this step (cached loads; inp is read-only)
        float xv[4][3];
        if (w < 4) {
            #pragma unroll
            for (int r = 0; r < 4; ++r) {
                const float* xp = inp + ((long)t * Bn + 16 * w + quad * 4 + r) * 3;
                xv[r][0] = xp[0]; xv[r][1] = xp[1]; xv[r][2] = xp[2];
            }
        }

        f32x4 acc[4][3];
        #pragma unroll
        for (int mt = 0; mt < 4; ++mt)
            #pragma unroll
            for (int nt = 0; nt < 3; ++nt)
                acc[mt][nt] = f32x4{0.f, 0.f, 0.f, 0.f};

        // wave's A-frag base: frag f=(k*4+mt) at short-offset f*512 + lane*8
        const unsigned short* pa = hcur + (long)(w * 8 * 4 * 64 + lane) * 8;

        // ---- 2 asm-pinned bursts: 16x dwordx4 loads, waitcnt, 48 MFMAs ----
        i32x4 hb[16];
        #pragma unroll
        for (int half = 0; half < 2; ++half) {
            const unsigned short* ph = pa + (long)(half * 16) * 512;
            #pragma unroll
            for (int f = 0; f < 16; ++f) {
                asm volatile("global_load_dwordx4 %0, %1, off sc0 sc1"
                             : "=v"(hb[f]) : "v"(ph + (long)f * 512) : "memory");
            }
            asm volatile("s_waitcnt vmcnt(0)"
                         : "+v"(hb[0]), "+v"(hb[1]), "+v"(hb[2]), "+v"(hb[3]),
                           "+v"(hb[4]), "+v"(hb[5]), "+v"(hb[6]), "+v"(hb[7]),
                           "+v"(hb[8]), "+v"(hb[9]), "+v"(hb[10]), "+v"(hb[11]),
                           "+v"(hb[12]), "+v"(hb[13]), "+v"(hb[14]), "+v"(hb[15])
                         :: "memory");
            #pragma unroll
            for (int k4i = 0; k4i < 4; ++k4i) {
                const int k = half * 4 + k4i;
                #pragma unroll
                for (int mt = 0; mt < 4; ++mt) {
                    union { i32x4 q; bf16x8 v; } u;
                    u.q = hb[k4i * 4 + mt];
                    bf16x8 a = u.v;
                    acc[mt][0] = __builtin_amdgcn_mfma_f32_16x16x32_bf16(a, Bf[0][k], acc[mt][0], 0, 0, 0);
                    acc[mt][1] = __builtin_amdgcn_mfma_f32_16x16x32_bf16(a, Bf[1][k], acc[mt][1], 0, 0, 0);
                    acc[mt][2] = __builtin_amdgcn_mfma_f32_16x16x32_bf16(a, Bf[2][k], acc[mt][2], 0, 0, 0);
                }
            }
        }

        // ---- two-round cross-wave K reduction through LDS (48 KB) ----
        if (w >= 4) {
            #pragma unroll
            for (int mt = 0; mt < 4; ++mt)
                #pragma unroll
                for (int nt = 0; nt < 3; ++nt)
                    red[w - 4][mt][nt][lane] = acc[mt][nt];
        }
        __syncthreads();
        if (w < 4) {
            #pragma unroll
            for (int mt = 0; mt < 4; ++mt)
                #pragma unroll
                for (int nt = 0; nt < 3; ++nt)
                    acc[mt][nt] += red[w][mt][nt][lane];
        }
        __syncthreads();
        if (w < 4) {
            #pragma unroll
            for (int mt = 0; mt < 4; ++mt)
                #pragma unroll
                for (int nt = 0; nt < 3; ++nt)
                    red[w][mt][nt][lane] = acc[mt][nt];
        }
        __syncthreads();

        if (w < 4) {
            f32x4 s0 = red[0][w][0][lane], s1 = red[0][w][1][lane], s2 = red[0][w][2][lane];
            #pragma unroll
            for (int src = 1; src < 4; ++src) {
                s0 += red[src][w][0][lane];
                s1 += red[src][w][1][lane];
                s2 += red[src][w][2][lane];
            }
            #pragma unroll
            for (int r = 0; r < 4; ++r) {
                const int b = 16 * w + quad * 4 + r;
                float pr = br_ + wr0*xv[r][0] + wr1*xv[r][1] + wr2*xv[r][2] + s0[r];
                float pz = bz_ + wz0*xv[r][0] + wz1*xv[r][1] + wz2*xv[r][2] + s1[r];
                float rr = sigm(pr);
                float zz = sigm(pz);
                float pn = bn2_ + wn0*xv[r][0] + wn1*xv[r][1] + wn2*xv[r][2] + rr * (s2[r] + bnn_);
                float nn = tanh_f(pn);
                float hv = nn + zz * (hst[r] - nn);
                hst[r] = hv;
                store_short_wt(hnext + ((long)((kkE * 4 + w) * 64) + qE * 16 + quad * 4 + r) * 8 + eE,
                               (unsigned)f2b(hv));
                if (blockIdx.x == 0 && n16 == 0)
                    store_dword_wt(out + t * Bn + b, hv);
            }
        }

        // ---- grid barrier: all signals via RMW, all polls via RMW(+0) ----
        __syncthreads();   // drains vmcnt(0) per wave -> WT stores at MALL
        if (tid == 0) {
            const unsigned tgt = (unsigned)(t + 1);
            unsigned old = __hip_atomic_fetch_add(&ctrl[LEAF_CTR(leaf)], 1u,
                                                  __ATOMIC_RELAXED, __HIP_MEMORY_SCOPE_SYSTEM);
            unsigned spins = 0;
            if ((old & 7) == 7) {      // this block closed its leaf
                __hip_atomic_fetch_add(&ctrl[ROOT_CTR], 1u,
                                       __ATOMIC_RELAXED, __HIP_MEMORY_SCOPE_SYSTEM);
                // poll the root COUNTER directly (no flag hop): 16 pollers
                while (poll_read(&ctrl[ROOT_CTR]) < 16u * tgt) {
                    __builtin_amdgcn_s_sleep(1);
                    if (++spins > SPIN_LIMIT) break;   // watchdog
                }
                __hip_atomic_fetch_add(&ctrl[LEAF_FLAG(leaf)], 1u,
                                       __ATOMIC_RELAXED, __HIP_MEMORY_SCOPE_SYSTEM);
            } else {
                while (poll_read(&ctrl[LEAF_FLAG(leaf)]) < tgt) {
                    __builtin_amdgcn_s_sleep(1);
                    if (++spins > SPIN_LIMIT) break;   // watchdog
                }
            }
        }
        __syncthreads();
    }
}

extern "C" void kernel_launch(void* const* d_in, const int* in_sizes, int n_in,
                              void* d_out, int out_size, void* d_ws, size_t ws_size,
                              hipStream_t stream) {
    const float* inp    = (const float*)d_in[0];  // [1024][64][3]
    const float* init_h = (const float*)d_in[1];  // [64][2048]
    const float* w_ih   = (const float*)d_in[2];  // [6144][3]
    const float* w_hh   = (const float*)d_in[3];  // [6144][2048]
    const float* bias   = (const float*)d_in[4];  // [6144]
    const float* bias_n = (const float*)d_in[5];  // [2048]
    float* out = (float*)d_out;                   // [1024][64]

    unsigned short* h0 = (unsigned short*)d_ws;          // 262144 B
    unsigned short* h1 = h0 + 131072L;                   // 262144 B
    unsigned* ctrl     = (unsigned*)(h1 + 131072L);      // 8192 B

    prep_kernel<<<128, 256, 0, stream>>>(init_h, h0, ctrl);
    gru_kernel<<<NBLK, NTHR, 0, stream>>>(inp, init_h, w_ih, w_hh, bias, bias_n,
                                          h0, h1, ctrl, out);
}